// Round 5
// baseline (180.011 us; speedup 1.0000x reference)
//
#include <hip/hip_runtime.h>

// B=128, A=512, N=256.
// out[b,a,n] = r_ij[b,a,n] + f(zi, zj), f has only 89*89 distinct values
// -> f16 LDS table (built once into d_ws).
// R5: steady-state memory pipeline, zero block churn.
//   grid = 1024 = exactly 4 resident blocks/CU (one generation, preamble once).
//   Each wave: 16 rows as 4 clusters of 4, rolling 2-cluster register double
//   buffer -> 8-16 outstanding 1KB loads per wave for the whole kernel
//   (R4 was burst-16-then-drain). Plain loads (inputs are L3-hot from the
//   harness restore), nontemporal stores (never re-read; don't evict inputs).
//   launch_bounds(256,4) => 128 VGPR budget (R3 failed because (256,8)=64cap).

#define BB 128
#define AA 512
#define NN 256
#define ROWS 64            // rows per block -> grid = 128*512/64 = 1024
#define TPB 256
#define TABN 8192          // 90*90=8100 rounded up for clean 16B-vector copy

typedef int   v4i __attribute__((ext_vector_type(4)));
typedef float v4f __attribute__((ext_vector_type(4)));

__device__ __forceinline__ float tab_entry(int idx) {
    int zi = idx / 90, zj = idx - zi * 90;
    float p = fmaxf((float)(zi * zj), 1.0f);
    float s = fmaxf((float)(zi + zj), 1.0f);
    const float c = -0.05f * 2.718281828459045f;
    return __expf(c * __powf(p, 1.01f) / __powf(s, 1.1f));
}

__global__ void RAN_72567767433723_build_tab(_Float16* __restrict__ tabg) {
    int idx = blockIdx.x * blockDim.x + threadIdx.x;
    tabg[idx] = (_Float16)tab_entry(idx);
}

template <bool LOAD_TAB>
__global__ __launch_bounds__(TPB, 4) void RAN_72567767433723_kernel(
    const float* __restrict__ an,
    const int*   __restrict__ nbrs,
    const float* __restrict__ rij,
    float*       __restrict__ out,
    const _Float16* __restrict__ tabg)
{
    __shared__ _Float16       tab[TABN];  // 16384 B
    __shared__ unsigned short zz[AA];     //  1024 B -> 17408 B total

    const int tid      = threadIdx.x;
    const int b        = blockIdx.x >> 3;            // 8 blocks per batch
    const int row_base = (blockIdx.x & 7) * ROWS;

    if (LOAD_TAB) {
        #pragma unroll
        for (int i = 0; i < TABN * 2 / (16 * TPB); ++i) {  // 4 iters, 16B/lane
            int k = i * TPB + tid;
            ((v4i*)tab)[k] = ((const v4i*)tabg)[k];
        }
    } else {
        for (int idx = tid; idx < TABN; idx += TPB)
            tab[idx] = (_Float16)tab_entry(idx);
    }
    #pragma unroll
    for (int i = tid; i < AA; i += TPB)
        zz[i] = (unsigned short)(int)(an[b * AA + i] + 0.5f);
    __syncthreads();

    const int w  = tid >> 6;             // wave id 0..3
    const int l  = tid & 63;             // float4 slot in row (N/4 = 64)
    const int a0 = row_base + w;         // wave w: rows a0 + 4*it, it=0..15
    const size_t base = ((size_t)(b * AA + a0)) * NN + (size_t)(l * 4);

    // Rolling 2-cluster register double buffer; cluster = 4 rows.
    v4i nb[2][4]; v4f rj[2][4];

    #pragma unroll
    for (int j = 0; j < 4; ++j) {        // prologue: clusters 0 and 1
        const size_t e0 = base + (size_t)(j * 4) * NN;
        const size_t e1 = base + (size_t)((4 + j) * 4) * NN;
        nb[0][j] = *(const v4i*)(nbrs + e0);
        rj[0][j] = *(const v4f*)(rij + e0);
        nb[1][j] = *(const v4i*)(nbrs + e1);
        rj[1][j] = *(const v4f*)(rij + e1);
    }

    #pragma unroll
    for (int c = 0; c < 4; ++c) {        // fully unrolled, branch-free
        const int buf = c & 1;

        #pragma unroll
        for (int j = 0; j < 4; ++j) {    // consume cluster c
            const int it = c * 4 + j;
            const int tb = (int)zz[a0 + it * 4] * 90;   // wave-uniform broadcast
            const size_t e = base + (size_t)(it * 4) * NN;
            v4f o;
            o.x = rj[buf][j].x + (float)tab[tb + (int)zz[nb[buf][j].x]];
            o.y = rj[buf][j].y + (float)tab[tb + (int)zz[nb[buf][j].y]];
            o.z = rj[buf][j].z + (float)tab[tb + (int)zz[nb[buf][j].z]];
            o.w = rj[buf][j].w + (float)tab[tb + (int)zz[nb[buf][j].w]];
            __builtin_nontemporal_store(o, (v4f*)(out + e));
        }

        if (c < 2) {                     // refill with cluster c+2 (compile-time)
            #pragma unroll
            for (int j = 0; j < 4; ++j) {
                const size_t e = base + (size_t)(((c + 2) * 4 + j) * 4) * NN;
                nb[buf][j] = *(const v4i*)(nbrs + e);
                rj[buf][j] = *(const v4f*)(rij + e);
            }
        }
    }
}

extern "C" void kernel_launch(void* const* d_in, const int* in_sizes, int n_in,
                              void* d_out, int out_size, void* d_ws, size_t ws_size,
                              hipStream_t stream) {
    const float* an  = (const float*)d_in[0];
    const int*   nbr = (const int*)d_in[1];
    const float* rij = (const float*)d_in[2];
    float*       o   = (float*)d_out;

    const int grid = (BB * AA) / ROWS;   // 1024

    if (ws_size >= (size_t)TABN * sizeof(_Float16)) {
        _Float16* tabg = (_Float16*)d_ws;
        RAN_72567767433723_build_tab<<<TABN / TPB, TPB, 0, stream>>>(tabg);
        RAN_72567767433723_kernel<true><<<grid, TPB, 0, stream>>>(an, nbr, rij, o, tabg);
    } else {
        RAN_72567767433723_kernel<false><<<grid, TPB, 0, stream>>>(an, nbr, rij, o, nullptr);
    }
}

// Round 6
// 165.618 us; speedup vs baseline: 1.0869x; 1.0869x over previous
//
#include <hip/hip_runtime.h>

// B=128, A=512, N=256.
// out[b,a,n] = r_ij[b,a,n] + f(zi, zj), f has only 89*89 distinct values
// -> f16 LDS table, built once into d_ws by a tiny pre-kernel.
// R6 = R4 + __builtin_amdgcn_sched_barrier(0) between the 16-load burst and
// the consume phase. R3/R5 post-mortems showed the LLVM scheduler ALWAYS
// sinks prefetch loads to just-before-use (VGPR 24/36), silently reducing
// per-wave MLP to ~2; the sched_barrier forbids crossing, forcing all 16
// load results live (VGPR should jump to ~90-110) and exposing ~one HBM
// latency per wave instead of eight.

#define BB 128
#define AA 512
#define NN 256
#define ROWS 32            // a-rows per block -> grid = 2048
#define TPB 256
#define TABN 8192          // 90*90=8100 rounded up for clean 16B-vector copy

typedef int   v4i __attribute__((ext_vector_type(4)));
typedef float v4f __attribute__((ext_vector_type(4)));

__device__ __forceinline__ float tab_entry(int idx) {
    int zi = idx / 90, zj = idx - zi * 90;
    float p = fmaxf((float)(zi * zj), 1.0f);
    float s = fmaxf((float)(zi + zj), 1.0f);
    const float c = -0.05f * 2.718281828459045f;
    return __expf(c * __powf(p, 1.01f) / __powf(s, 1.1f));
}

__global__ void RAN_72567767433723_build_tab(_Float16* __restrict__ tabg) {
    int idx = blockIdx.x * blockDim.x + threadIdx.x;
    tabg[idx] = (_Float16)tab_entry(idx);
}

template <bool LOAD_TAB>
__global__ __launch_bounds__(TPB, 4) void RAN_72567767433723_kernel(
    const float* __restrict__ an,
    const int*   __restrict__ nbrs,
    const float* __restrict__ rij,
    float*       __restrict__ out,
    const _Float16* __restrict__ tabg)
{
    __shared__ _Float16       tab[TABN];  // 16384 B
    __shared__ unsigned short zz[AA];     //  1024 B -> 17408 B total

    const int tid      = threadIdx.x;
    const int b        = blockIdx.x >> 4;            // 16 blocks per batch
    const int row_base = (blockIdx.x & 15) * ROWS;

    if (LOAD_TAB) {
        #pragma unroll
        for (int i = 0; i < TABN * 2 / (16 * TPB); ++i) {  // 4 iters, 16B/lane
            int k = i * TPB + tid;
            ((v4i*)tab)[k] = ((const v4i*)tabg)[k];
        }
    } else {
        for (int idx = tid; idx < TABN; idx += TPB)
            tab[idx] = (_Float16)tab_entry(idx);
    }
    #pragma unroll
    for (int i = tid; i < AA; i += TPB)
        zz[i] = (unsigned short)(int)(an[b * AA + i] + 0.5f);
    __syncthreads();

    const int w  = tid >> 6;             // wave id 0..3
    const int l  = tid & 63;             // float4 slot in row (N/4 = 64)
    const int a0 = row_base + w;         // wave w: rows a0 + 4*it, it=0..7
    const size_t base = ((size_t)(b * AA + a0)) * NN + (size_t)(l * 4);

    // Phase 1: issue ALL global loads (16 x 16B/lane in flight).
    v4i nb[8]; v4f rj[8];
    #pragma unroll
    for (int it = 0; it < 8; ++it) {
        const size_t e = base + (size_t)(it * 4) * NN;
        nb[it] = __builtin_nontemporal_load((const v4i*)(nbrs + e));
        rj[it] = __builtin_nontemporal_load((const v4f*)(rij + e));
    }

    // Row-base table offsets (wave-uniform LDS broadcasts, independent of
    // the global loads -> issue them inside the latency shadow).
    int tb[8];
    #pragma unroll
    for (int it = 0; it < 8; ++it)
        tb[it] = (int)zz[a0 + it * 4] * 90;

    // Fence: nothing may cross. Forces the 16 load results to stay live
    // (defeats the scheduler's load-sinking seen in R3/R5).
    __builtin_amdgcn_sched_barrier(0);

    // Phase 2: LDS gathers + stores, consuming loads in issue order.
    #pragma unroll
    for (int it = 0; it < 8; ++it) {
        const size_t e = base + (size_t)(it * 4) * NN;
        v4f o;
        o.x = rj[it].x + (float)tab[tb[it] + (int)zz[nb[it].x]];
        o.y = rj[it].y + (float)tab[tb[it] + (int)zz[nb[it].y]];
        o.z = rj[it].z + (float)tab[tb[it] + (int)zz[nb[it].z]];
        o.w = rj[it].w + (float)tab[tb[it] + (int)zz[nb[it].w]];
        __builtin_nontemporal_store(o, (v4f*)(out + e));
    }
}

extern "C" void kernel_launch(void* const* d_in, const int* in_sizes, int n_in,
                              void* d_out, int out_size, void* d_ws, size_t ws_size,
                              hipStream_t stream) {
    const float* an  = (const float*)d_in[0];
    const int*   nbr = (const int*)d_in[1];
    const float* rij = (const float*)d_in[2];
    float*       o   = (float*)d_out;

    const int grid = (BB * AA) / ROWS;   // 2048

    if (ws_size >= (size_t)TABN * sizeof(_Float16)) {
        _Float16* tabg = (_Float16*)d_ws;
        RAN_72567767433723_build_tab<<<TABN / TPB, TPB, 0, stream>>>(tabg);
        RAN_72567767433723_kernel<true><<<grid, TPB, 0, stream>>>(an, nbr, rij, o, tabg);
    } else {
        RAN_72567767433723_kernel<false><<<grid, TPB, 0, stream>>>(an, nbr, rij, o, nullptr);
    }
}